// Round 2
// baseline (521.888 us; speedup 1.0000x reference)
//
#include <hip/hip_runtime.h>
#include <math.h>

// Problem constants
#define EPS 1e-8f
// inputs: [B=2, C=32, D=96, H=96, W=96] fp32, pooled to S=8 per axis (12^3 blocks)
// tokens L = 512, channels C = 32

// ---------------------------------------------------------------------------
// Kernel A: adaptive avg-pool 96^3 -> 8^3, write f[inp][b][l][c] (l = z*64+y*8+x)
// grid.x = 2048 = inp(2) * b(2) * c(32) * z(8), 256 threads.
// Each block reads one z-slab: 12 planes x 96x96 floats = 27648 float4 (432 KB).
// Per plane: thread t loads f4[t + 256k], k=0..8 -> 9 independent, perfectly
// coalesced dwordx4 loads in flight (1 KiB/wave/instruction). Bucket mapping
// (h/12, x4/3) is resolved in a cheap LDS epilogue, NOT in the load pattern.
// R0 lesson: VGPR_Count=12 meant the compiler serialized loads -> latency
// bound at 1.6 TB/s. Explicit v[9] array forces ~9 outstanding loads.
// ---------------------------------------------------------------------------
__global__ __launch_bounds__(256) void k_pool(const float* __restrict__ p1,
                                              const float* __restrict__ p2,
                                              float* __restrict__ fpool) {
    int gid = blockIdx.x;
    int z   = gid & 7;
    int c   = (gid >> 3) & 31;
    int b   = (gid >> 8) & 1;
    int inp = gid >> 9;
    const float4* p4 = reinterpret_cast<const float4*>(inp ? p2 : p1);
    // base in float4 units: plane = 96*96/4 = 2304 f4; channel = 96 planes
    int base4 = ((b * 32 + c) * 96 + z * 12) * 2304;

    int t = threadIdx.x;
    float acc[9];
#pragma unroll
    for (int k = 0; k < 9; k++) acc[k] = 0.f;

    for (int d = 0; d < 12; d++) {
        const float4* pp = p4 + base4 + d * 2304 + t;
        float4 v[9];
#pragma unroll
        for (int k = 0; k < 9; k++) v[k] = pp[k * 256];   // all loads issued first
#pragma unroll
        for (int k = 0; k < 9; k++)
            acc[k] += (v[k].x + v[k].y) + (v[k].z + v[k].w);
    }

    // acc[k] = sum over 12 planes of the 4 floats at linear f4 pos j = t + 256k
    // within a plane. j -> row h = j/24, x4 = j%24; bucket = (h/12, x4/3).
    __shared__ float sh[2304];
#pragma unroll
    for (int k = 0; k < 9; k++) sh[t + 256 * k] = acc[k];
    __syncthreads();

    if (t < 64) {
        int by = t >> 3, bx = t & 7;
        float s = 0.f;
#pragma unroll
        for (int r = 0; r < 12; r++) {
            int base = (12 * by + r) * 24 + 3 * bx;
            s += sh[base] + sh[base + 1] + sh[base + 2];
        }
        int l = z * 64 + by * 8 + bx;
        fpool[(((inp * 2 + b) * 512 + l) << 5) + c] = s * (1.f / 1728.f);
    }
}

// ---------------------------------------------------------------------------
// Kernel B: per-token L2 norms over 32 channels. 2048 tokens total.
// Also zeroes the scalar output (d_out is poisoned 0xAA before every launch).
// ---------------------------------------------------------------------------
__global__ __launch_bounds__(256) void k_norm(const float* __restrict__ fpool,
                                              float* __restrict__ nrm,
                                              float* __restrict__ out) {
    int idx = blockIdx.x * 256 + threadIdx.x;  // [0,2048)
    if (idx == 0) out[0] = 0.f;
    const float4* f4 = reinterpret_cast<const float4*>(fpool + idx * 32);
    float s = 0.f;
#pragma unroll
    for (int i = 0; i < 8; i++) {
        float4 v = f4[i];
        s += v.x * v.x + v.y * v.y + v.z * v.z + v.w * v.w;
    }
    nrm[idx] = sqrtf(s);
}

// ---------------------------------------------------------------------------
// Kernel C: pairwise cosine sims for both inputs + accumulate MSE.
// grid = (32 m-tiles, 32 l-tiles, 2 batches), 256 threads = 16x16 pairs.
// LDS tiles padded [16][33] to break the stride-32 16-way bank conflict.
// ---------------------------------------------------------------------------
__global__ __launch_bounds__(256) void k_loss(const float* __restrict__ fpool,
                                              const float* __restrict__ nrm,
                                              float* __restrict__ out) {
    int b  = blockIdx.z;
    int lt = blockIdx.y * 16;
    int mt = blockIdx.x * 16;

    __shared__ float Al[16][33], Am[16][33], Bl[16][33], Bm[16][33];
    __shared__ float nAl[16], nAm[16], nBl[16], nBm[16];

    int t = threadIdx.x;
    int row = t >> 4;
    int c0 = (t & 15) << 1;  // two consecutive channels per thread
    const float2* f2 = reinterpret_cast<const float2*>(fpool);
    int h = c0 >> 1;
    int oAl = ((0 * 2 + b) * 512 + lt + row) * 16 + h;
    int oAm = ((0 * 2 + b) * 512 + mt + row) * 16 + h;
    int oBl = ((1 * 2 + b) * 512 + lt + row) * 16 + h;
    int oBm = ((1 * 2 + b) * 512 + mt + row) * 16 + h;
    float2 v;
    v = f2[oAl]; Al[row][c0] = v.x; Al[row][c0 + 1] = v.y;
    v = f2[oAm]; Am[row][c0] = v.x; Am[row][c0 + 1] = v.y;
    v = f2[oBl]; Bl[row][c0] = v.x; Bl[row][c0 + 1] = v.y;
    v = f2[oBm]; Bm[row][c0] = v.x; Bm[row][c0 + 1] = v.y;
    if (t < 16) {
        nAl[t] = nrm[(0 * 2 + b) * 512 + lt + t];
        nAm[t] = nrm[(0 * 2 + b) * 512 + mt + t];
        nBl[t] = nrm[(1 * 2 + b) * 512 + lt + t];
        nBm[t] = nrm[(1 * 2 + b) * 512 + mt + t];
    }
    __syncthreads();

    int tl = t >> 4, tm = t & 15;
    float da = 0.f, db = 0.f;
#pragma unroll
    for (int c = 0; c < 32; c++) {
        da += Al[tl][c] * Am[tm][c];
        db += Bl[tl][c] * Bm[tm][c];
    }
    float dena = fmaxf(nAl[tl] * nAm[tm], EPS);
    float denb = fmaxf(nBl[tl] * nBm[tm], EPS);
    float diff = da / dena - db / denb;
    float val = diff * diff * (1.f / (512.f * 512.f * 2.f));

    // block reduction -> one atomic per block
#pragma unroll
    for (int m = 1; m < 64; m <<= 1) val += __shfl_xor(val, m);
    __shared__ float red[4];
    if ((t & 63) == 0) red[t >> 6] = val;
    __syncthreads();
    if (t == 0) atomicAdd(out, red[0] + red[1] + red[2] + red[3]);
}

extern "C" void kernel_launch(void* const* d_in, const int* in_sizes, int n_in,
                              void* d_out, int out_size, void* d_ws, size_t ws_size,
                              hipStream_t stream) {
    const float* p1 = (const float*)d_in[0];
    const float* p2 = (const float*)d_in[1];
    float* out = (float*)d_out;

    // workspace layout: fpool [2][2][512][32] floats (256 KB), then nrm [2048] floats
    float* fpool = (float*)d_ws;
    float* nrm = fpool + 2 * 2 * 512 * 32;

    k_pool<<<2048, 256, 0, stream>>>(p1, p2, fpool);
    k_norm<<<8, 256, 0, stream>>>(fpool, nrm, out);
    k_loss<<<dim3(32, 32, 2), 256, 0, stream>>>(fpool, nrm, out);
}

// Round 3
// 467.047 us; speedup vs baseline: 1.1174x; 1.1174x over previous
//
#include <hip/hip_runtime.h>
#include <math.h>

// Problem constants
#define EPS 1e-8f
// inputs: [B=2, C=32, D=96, H=96, W=96] fp32, pooled to S=8 per axis (12^3 blocks)
// tokens L = 512, channels C = 32

// ---------------------------------------------------------------------------
// Kernel A: adaptive avg-pool 96^3 -> 8^3, write f[inp][b][l][c] (l = z*64+y*8+x)
// grid.x = 1024 = inp(2) * b(2) * c(32) * z(8), 256 threads.   <-- R2 bug was
// 2048 blocks here: half the grid re-read p2 (906 MB streamed at 4.46 TB/s).
// Each block reads one z-slab: 12 planes x 2304 float4 = 442 KB contiguous.
// Per plane: thread t loads f4[t + 256k], k=0..8 -> 9 independent, perfectly
// coalesced dwordx4 loads. float4 accumulators acc4[9] (not scalar) prevent
// the compiler from folding load->add into one reused register (R2: VGPR=32,
// loads serialized); distinct vector accumulators keep all 9 loads in flight.
// ---------------------------------------------------------------------------
__global__ __launch_bounds__(256) void k_pool(const float* __restrict__ p1,
                                              const float* __restrict__ p2,
                                              float* __restrict__ fpool) {
    int gid = blockIdx.x;          // [0, 1024)
    int z   = gid & 7;
    int c   = (gid >> 3) & 31;
    int b   = (gid >> 8) & 1;
    int inp = gid >> 9;            // {0,1}
    const float4* p4 = reinterpret_cast<const float4*>(inp ? p2 : p1);
    // base in float4 units: plane = 96*96/4 = 2304 f4; channel = 96 planes
    int base4 = ((b * 32 + c) * 96 + z * 12) * 2304;

    int t = threadIdx.x;
    float4 acc4[9];
#pragma unroll
    for (int k = 0; k < 9; k++) acc4[k] = make_float4(0.f, 0.f, 0.f, 0.f);

    for (int d = 0; d < 12; d++) {
        const float4* pp = p4 + base4 + d * 2304 + t;
        float4 v[9];
#pragma unroll
        for (int k = 0; k < 9; k++) v[k] = pp[k * 256];   // all 9 issued first
#pragma unroll
        for (int k = 0; k < 9; k++) {
            acc4[k].x += v[k].x;
            acc4[k].y += v[k].y;
            acc4[k].z += v[k].z;
            acc4[k].w += v[k].w;
        }
    }

    // acc4[k] = per-lane column sums over 12 planes at linear f4 pos j = t+256k.
    // j -> row h = j/24, x4 = j%24; bucket = (h/12, x4/3). Resolve via LDS.
    __shared__ float sh[2304];
#pragma unroll
    for (int k = 0; k < 9; k++)
        sh[t + 256 * k] = (acc4[k].x + acc4[k].y) + (acc4[k].z + acc4[k].w);
    __syncthreads();

    if (t < 64) {
        int by = t >> 3, bx = t & 7;
        float s = 0.f;
#pragma unroll
        for (int r = 0; r < 12; r++) {
            int base = (12 * by + r) * 24 + 3 * bx;
            s += sh[base] + sh[base + 1] + sh[base + 2];
        }
        int l = z * 64 + by * 8 + bx;
        fpool[(((inp * 2 + b) * 512 + l) << 5) + c] = s * (1.f / 1728.f);
    }
}

// ---------------------------------------------------------------------------
// Kernel B: per-token L2 norms over 32 channels. 2048 tokens total.
// Also zeroes the scalar output (d_out is poisoned 0xAA before every launch).
// ---------------------------------------------------------------------------
__global__ __launch_bounds__(256) void k_norm(const float* __restrict__ fpool,
                                              float* __restrict__ nrm,
                                              float* __restrict__ out) {
    int idx = blockIdx.x * 256 + threadIdx.x;  // [0,2048)
    if (idx == 0) out[0] = 0.f;
    const float4* f4 = reinterpret_cast<const float4*>(fpool + idx * 32);
    float s = 0.f;
#pragma unroll
    for (int i = 0; i < 8; i++) {
        float4 v = f4[i];
        s += v.x * v.x + v.y * v.y + v.z * v.z + v.w * v.w;
    }
    nrm[idx] = sqrtf(s);
}

// ---------------------------------------------------------------------------
// Kernel C: pairwise cosine sims for both inputs + accumulate MSE.
// grid = (32 m-tiles, 32 l-tiles, 2 batches), 256 threads = 16x16 pairs.
// LDS tiles padded [16][33] to break the stride-32 16-way bank conflict.
// ---------------------------------------------------------------------------
__global__ __launch_bounds__(256) void k_loss(const float* __restrict__ fpool,
                                              const float* __restrict__ nrm,
                                              float* __restrict__ out) {
    int b  = blockIdx.z;
    int lt = blockIdx.y * 16;
    int mt = blockIdx.x * 16;

    __shared__ float Al[16][33], Am[16][33], Bl[16][33], Bm[16][33];
    __shared__ float nAl[16], nAm[16], nBl[16], nBm[16];

    int t = threadIdx.x;
    int row = t >> 4;
    int c0 = (t & 15) << 1;  // two consecutive channels per thread
    const float2* f2 = reinterpret_cast<const float2*>(fpool);
    int h = c0 >> 1;
    int oAl = ((0 * 2 + b) * 512 + lt + row) * 16 + h;
    int oAm = ((0 * 2 + b) * 512 + mt + row) * 16 + h;
    int oBl = ((1 * 2 + b) * 512 + lt + row) * 16 + h;
    int oBm = ((1 * 2 + b) * 512 + mt + row) * 16 + h;
    float2 v;
    v = f2[oAl]; Al[row][c0] = v.x; Al[row][c0 + 1] = v.y;
    v = f2[oAm]; Am[row][c0] = v.x; Am[row][c0 + 1] = v.y;
    v = f2[oBl]; Bl[row][c0] = v.x; Bl[row][c0 + 1] = v.y;
    v = f2[oBm]; Bm[row][c0] = v.x; Bm[row][c0 + 1] = v.y;
    if (t < 16) {
        nAl[t] = nrm[(0 * 2 + b) * 512 + lt + t];
        nAm[t] = nrm[(0 * 2 + b) * 512 + mt + t];
        nBl[t] = nrm[(1 * 2 + b) * 512 + lt + t];
        nBm[t] = nrm[(1 * 2 + b) * 512 + mt + t];
    }
    __syncthreads();

    int tl = t >> 4, tm = t & 15;
    float da = 0.f, db = 0.f;
#pragma unroll
    for (int c = 0; c < 32; c++) {
        da += Al[tl][c] * Am[tm][c];
        db += Bl[tl][c] * Bm[tm][c];
    }
    float dena = fmaxf(nAl[tl] * nAm[tm], EPS);
    float denb = fmaxf(nBl[tl] * nBm[tm], EPS);
    float diff = da / dena - db / denb;
    float val = diff * diff * (1.f / (512.f * 512.f * 2.f));

    // block reduction -> one atomic per block
#pragma unroll
    for (int m = 1; m < 64; m <<= 1) val += __shfl_xor(val, m);
    __shared__ float red[4];
    if ((t & 63) == 0) red[t >> 6] = val;
    __syncthreads();
    if (t == 0) atomicAdd(out, red[0] + red[1] + red[2] + red[3]);
}

extern "C" void kernel_launch(void* const* d_in, const int* in_sizes, int n_in,
                              void* d_out, int out_size, void* d_ws, size_t ws_size,
                              hipStream_t stream) {
    const float* p1 = (const float*)d_in[0];
    const float* p2 = (const float*)d_in[1];
    float* out = (float*)d_out;

    // workspace layout: fpool [2][2][512][32] floats (256 KB), then nrm [2048] floats
    float* fpool = (float*)d_ws;
    float* nrm = fpool + 2 * 2 * 512 * 32;

    k_pool<<<1024, 256, 0, stream>>>(p1, p2, fpool);
    k_norm<<<8, 256, 0, stream>>>(fpool, nrm, out);
    k_loss<<<dim3(32, 32, 2), 256, 0, stream>>>(fpool, nrm, out);
}

// Round 4
// 462.000 us; speedup vs baseline: 1.1296x; 1.0109x over previous
//
#include <hip/hip_runtime.h>
#include <math.h>

// Problem constants
#define EPS 1e-8f
// inputs: [B=2, C=32, D=96, H=96, W=96] fp32, pooled to S=8 per axis (12^3 blocks)
// tokens L = 512, channels C = 32
//
// R3 lesson: effective BW scales with resident waves (R2 64% occ -> 4.46 TB/s,
// R3 37% occ -> 3.1 TB/s; VGPR=32 both), NOT with source-level ILP (compiler
// collapses load/add chains to ~2 in flight regardless). So: more blocks.

// ---------------------------------------------------------------------------
// Kernel A: partial avg-pool. grid.x = 4096 = inp(2)*b(2)*c(32)*z(8)*dq(4),
// 256 threads. Each block reads 3 d-planes (110 KB contiguous) and emits 64
// unnormalized bucket partials: partial[gid*64 + (by*8+bx)].
// 8 blocks/CU resident (VGPR 32, LDS 9.2 KB) -> 32 waves/CU = 100% occupancy.
// ---------------------------------------------------------------------------
__global__ __launch_bounds__(256) void k_pool(const float* __restrict__ p1,
                                              const float* __restrict__ p2,
                                              float* __restrict__ partial) {
    int gid = blockIdx.x;          // [0, 4096)
    int dq  = gid & 3;             // which 3-plane quarter of the z-slab
    int z   = (gid >> 2) & 7;
    int c   = (gid >> 5) & 31;
    int b   = (gid >> 10) & 1;
    int inp = gid >> 11;           // {0,1}
    const float4* p4 = reinterpret_cast<const float4*>(inp ? p2 : p1);
    // plane = 96*96/4 = 2304 f4; channel = 96 planes; this block: planes z*12+dq*3 ..+3
    int base4 = ((b * 32 + c) * 96 + z * 12 + dq * 3) * 2304;

    int t = threadIdx.x;
    float4 acc4[9];
#pragma unroll
    for (int k = 0; k < 9; k++) acc4[k] = make_float4(0.f, 0.f, 0.f, 0.f);

#pragma unroll
    for (int d = 0; d < 3; d++) {
        const float4* pp = p4 + base4 + d * 2304 + t;
        float4 v[9];
#pragma unroll
        for (int k = 0; k < 9; k++) v[k] = pp[k * 256];   // coalesced 1 KB/wave each
#pragma unroll
        for (int k = 0; k < 9; k++) {
            acc4[k].x += v[k].x;
            acc4[k].y += v[k].y;
            acc4[k].z += v[k].z;
            acc4[k].w += v[k].w;
        }
    }

    // acc4[k] = per-lane sums over 3 planes at plane-linear f4 pos j = t+256k.
    // j -> row h = j/24, x4 = j%24; bucket = (h/12, x4/3). Resolve via LDS.
    __shared__ float sh[2304];
#pragma unroll
    for (int k = 0; k < 9; k++)
        sh[t + 256 * k] = (acc4[k].x + acc4[k].y) + (acc4[k].z + acc4[k].w);
    __syncthreads();

    if (t < 64) {
        int by = t >> 3, bx = t & 7;
        float s = 0.f;
#pragma unroll
        for (int r = 0; r < 12; r++) {
            int base = (12 * by + r) * 24 + 3 * bx;
            s += sh[base] + sh[base + 1] + sh[base + 2];
        }
        partial[(gid << 6) + t] = s;   // unnormalized; fold applies 1/1728
    }
}

// ---------------------------------------------------------------------------
// Kernel B: fold the 4 dq-partials per cell, normalize, write fpool and the
// per-token L2 norms. Also zeroes the scalar output. 2048 tokens; lane = yx
// so each (c,dq) read is a coalesced 256 B run. 1.25 MB traffic, L2-resident.
// ---------------------------------------------------------------------------
__global__ __launch_bounds__(256) void k_fold(const float* __restrict__ partial,
                                              float* __restrict__ fpool,
                                              float* __restrict__ nrm,
                                              float* __restrict__ out) {
    int idx = blockIdx.x * 256 + threadIdx.x;  // [0,2048) = (inp*2+b)*512 + z*64 + yx
    if (idx == 0) out[0] = 0.f;
    int yx = idx & 63;
    int z  = (idx >> 6) & 7;
    int ib = idx >> 9;                         // inp*2+b
    int tokbase = idx * 32;                    // fpool row for this token
    float ssum = 0.f;
#pragma unroll
    for (int c = 0; c < 32; c++) {
        int pbase = ((((ib * 32 + c) * 8 + z) * 4) << 6) + yx;
        float s = partial[pbase] + partial[pbase + 64]
                + partial[pbase + 128] + partial[pbase + 192];
        s *= (1.f / 1728.f);
        fpool[tokbase + c] = s;
        ssum += s * s;
    }
    nrm[idx] = sqrtf(ssum);
}

// ---------------------------------------------------------------------------
// Kernel C: pairwise cosine sims for both inputs + accumulate MSE.
// grid = (32 m-tiles, 32 l-tiles, 2 batches), 256 threads = 16x16 pairs.
// LDS tiles padded [16][33] to break the stride-32 16-way bank conflict.
// ---------------------------------------------------------------------------
__global__ __launch_bounds__(256) void k_loss(const float* __restrict__ fpool,
                                              const float* __restrict__ nrm,
                                              float* __restrict__ out) {
    int b  = blockIdx.z;
    int lt = blockIdx.y * 16;
    int mt = blockIdx.x * 16;

    __shared__ float Al[16][33], Am[16][33], Bl[16][33], Bm[16][33];
    __shared__ float nAl[16], nAm[16], nBl[16], nBm[16];

    int t = threadIdx.x;
    int row = t >> 4;
    int c0 = (t & 15) << 1;  // two consecutive channels per thread
    const float2* f2 = reinterpret_cast<const float2*>(fpool);
    int h = c0 >> 1;
    int oAl = ((0 * 2 + b) * 512 + lt + row) * 16 + h;
    int oAm = ((0 * 2 + b) * 512 + mt + row) * 16 + h;
    int oBl = ((1 * 2 + b) * 512 + lt + row) * 16 + h;
    int oBm = ((1 * 2 + b) * 512 + mt + row) * 16 + h;
    float2 v;
    v = f2[oAl]; Al[row][c0] = v.x; Al[row][c0 + 1] = v.y;
    v = f2[oAm]; Am[row][c0] = v.x; Am[row][c0 + 1] = v.y;
    v = f2[oBl]; Bl[row][c0] = v.x; Bl[row][c0 + 1] = v.y;
    v = f2[oBm]; Bm[row][c0] = v.x; Bm[row][c0 + 1] = v.y;
    if (t < 16) {
        nAl[t] = nrm[(0 * 2 + b) * 512 + lt + t];
        nAm[t] = nrm[(0 * 2 + b) * 512 + mt + t];
        nBl[t] = nrm[(1 * 2 + b) * 512 + lt + t];
        nBm[t] = nrm[(1 * 2 + b) * 512 + mt + t];
    }
    __syncthreads();

    int tl = t >> 4, tm = t & 15;
    float da = 0.f, db = 0.f;
#pragma unroll
    for (int c = 0; c < 32; c++) {
        da += Al[tl][c] * Am[tm][c];
        db += Bl[tl][c] * Bm[tm][c];
    }
    float dena = fmaxf(nAl[tl] * nAm[tm], EPS);
    float denb = fmaxf(nBl[tl] * nBm[tm], EPS);
    float diff = da / dena - db / denb;
    float val = diff * diff * (1.f / (512.f * 512.f * 2.f));

    // block reduction -> one atomic per block
#pragma unroll
    for (int m = 1; m < 64; m <<= 1) val += __shfl_xor(val, m);
    __shared__ float red[4];
    if ((t & 63) == 0) red[t >> 6] = val;
    __syncthreads();
    if (t == 0) atomicAdd(out, red[0] + red[1] + red[2] + red[3]);
}

extern "C" void kernel_launch(void* const* d_in, const int* in_sizes, int n_in,
                              void* d_out, int out_size, void* d_ws, size_t ws_size,
                              hipStream_t stream) {
    const float* p1 = (const float*)d_in[0];
    const float* p2 = (const float*)d_in[1];
    float* out = (float*)d_out;

    // workspace: fpool [2][2][512][32] (256 KB) | nrm [2048] | partial [4096*64] (1 MB)
    float* fpool = (float*)d_ws;
    float* nrm = fpool + 2 * 2 * 512 * 32;
    float* partial = nrm + 2048;

    k_pool<<<4096, 256, 0, stream>>>(p1, p2, partial);
    k_fold<<<8, 256, 0, stream>>>(partial, fpool, nrm, out);
    k_loss<<<dim3(32, 32, 2), 256, 0, stream>>>(fpool, nrm, out);
}